// Round 2
// baseline (1836.070 us; speedup 1.0000x reference)
//
#include <hip/hip_runtime.h>

// ---------------- workspace layout (floats) ----------------
#define WS_WT    0          // 640*64 transposed w1x1 [c][o]
#define WS_WSUM  40960      // 64 row sums of w1x1
#define WS_FB    41024      // 8*100*64   fb [b][hw][o]
#define WS_FM    92224      // 50*100*64  fm [n][ij][o]
#define WS_ATTN  412224     // 400*100 attn_memory [q][ij]
#define WS_AM    452224     // 8*50*640 att_mem [b][n][c]
#define WS_ENC   708224     // 8*640
#define WS_MV    713344     // 8*640

// ---------------- prep: transpose w1x1 + row sums ----------------
__global__ void k_prep(const float* __restrict__ w1x1, float* __restrict__ wT,
                       float* __restrict__ wsum) {
  if (blockIdx.x < 160) {
    int idx = blockIdx.x * 256 + threadIdx.x;   // < 40960
    int o = idx / 640, c = idx % 640;
    wT[c * 64 + o] = w1x1[idx];
  } else {
    int o = threadIdx.x;
    if (o < 64) {
      float s = 0.f;
      for (int c = 0; c < 640; ++c) s += w1x1[o * 640 + c];
      wsum[o] = s;
    }
  }
}

// ---------------- embed: mean-shift + 1x1 conv + BN + ReLU + L2 norm ----------
__global__ void k_embed(const float* __restrict__ fbg, const float* __restrict__ fmg,
                        const float* __restrict__ wT, const float* __restrict__ wsum,
                        const float* __restrict__ bns, const float* __restrict__ bnb,
                        float* __restrict__ fb, float* __restrict__ fm) {
  int lane = threadIdx.x;
  int pos0 = blockIdx.x * 10;
  const float* src; float* dst; int hw0;
  if (pos0 < 800) { int img = pos0 / 100; hw0 = pos0 % 100; src = fbg + img * 64000; dst = fb + pos0 * 64; }
  else { int p = pos0 - 800; int img = p / 100; hw0 = p % 100; src = fmg + img * 64000; dst = fm + p * 64; }

  __shared__ float xs[10][640];
  float lsum[10];
#pragma unroll
  for (int p = 0; p < 10; ++p) lsum[p] = 0.f;
  for (int i = 0; i < 10; ++i) {
    int c = lane + i * 64;
    const float* sp = src + c * 100 + hw0;
#pragma unroll
    for (int p = 0; p < 10; p += 2) {
      float2 v = *(const float2*)(sp + p);
      xs[p][c] = v.x; xs[p + 1][c] = v.y;
      lsum[p] += v.x; lsum[p + 1] += v.y;
    }
  }
  float mean[10];
#pragma unroll
  for (int p = 0; p < 10; ++p) {
    float s = lsum[p];
    for (int off = 32; off; off >>= 1) s += __shfl_down(s, off);
    mean[p] = __shfl(s, 0) * (1.f / 640.f);
  }
  __syncthreads();
  float acc[10];
#pragma unroll
  for (int p = 0; p < 10; ++p) acc[p] = 0.f;
  for (int c = 0; c < 640; ++c) {
    float w = wT[c * 64 + lane];
#pragma unroll
    for (int p = 0; p < 10; ++p) acc[p] += xs[p][c] * w;
  }
  float wsl = wsum[lane], sc = bns[lane], bi = bnb[lane];
#pragma unroll
  for (int p = 0; p < 10; ++p) {
    float y = (acc[p] - mean[p] * wsl) * sc + bi;
    y = fmaxf(y, 0.f);
    float sq = y * y;
    for (int off = 32; off; off >>= 1) sq += __shfl_down(sq, off);
    float nrm = sqrtf(__shfl(sq, 0));
    dst[p * 64 + lane] = y / fmaxf(nrm, 1e-8f);
  }
}

// ================= fused corr + sep-conv4d(x2) + attn-softmax ================
// grid 400 (one q), block 512. LDS ~126KB -> 1 block/CU, 8 waves, VGPR budget ~500.
// xs rows (u,v,h) stride 12 words (48B, b128-aligned, 3 quad-units -> conflict-free)

#define LOAD_ROW12(DST, BASE, OFFW, OK) {                                   \
    int _o = (OK) ? (OFFW) : 0;                                             \
    float4 _a = *(const float4*)((BASE) + _o);                              \
    float4 _b = *(const float4*)((BASE) + _o + 4);                          \
    float4 _c = *(const float4*)((BASE) + _o + 8);                          \
    if (!(OK)) { _a = make_float4(0,0,0,0); _b = _a; _c = _a; }             \
    DST[0]=_a.x; DST[1]=_a.y; DST[2]=_a.z; DST[3]=_a.w;                     \
    DST[4]=_b.x; DST[5]=_b.y; DST[6]=_b.z; DST[7]=_b.w;                     \
    DST[8]=_c.x; DST[9]=_c.y; }

#define HW_TAPS(OUT, ROW, W0, W1, W2) {                                     \
    _Pragma("unroll") for (int w = 1; w < 10; ++w) OUT[w] += (W0)*ROW[w-1]; \
    _Pragma("unroll") for (int w = 0; w < 10; ++w) OUT[w] += (W1)*ROW[w];   \
    _Pragma("unroll") for (int w = 0; w < 9;  ++w) OUT[w] += (W2)*ROW[w+1]; }

#define UV_TAPS(ACCARR, ROW, WARR) {                                        \
    _Pragma("unroll") for (int i = 0; i < 2; ++i) {                         \
      _Pragma("unroll") for (int j = 0; j < 2; ++j) {                       \
        int du = uu - 1 - i, dv = vv - 1 - j;                               \
        if (du >= -1 && du <= 1 && dv >= -1 && dv <= 1) {                   \
          float wgt = WARR[(du+1)*3 + (dv+1)];                              \
          _Pragma("unroll") for (int w = 0; w < 10; ++w)                    \
            ACCARR[i*2+j][w] += wgt * ROW[w];                               \
        } } } }

__global__ __launch_bounds__(512, 1) void k_mid(
    const float* __restrict__ fb, const float* __restrict__ fm,
    const float* __restrict__ w1h_g, const float* __restrict__ w1u_g,
    const float* __restrict__ w2h_g, const float* __restrict__ w2u_g,
    float* __restrict__ attn)
{
  __shared__ float xs[12000];    // corr, rows (u,v,h) stride 12
  __shared__ float c1[12000];    // per-k hidden; later reused as T[100][104]
  __shared__ float fbS[6800];    // fb rows stride 68
  __shared__ float wts[576];
  __shared__ float rcps[100];
  const int tid = threadIdx.x, q = blockIdx.x;
  const int b = q / 50, n = q % 50;

  // ---- stage fb rows + weights ----
  for (int i = tid; i < 1600; i += 512) {
    int hw = i >> 4, c4 = (i & 15) << 2;
    float4 v = *(const float4*)(fb + b * 6400 + hw * 64 + c4);
    *(float4*)(fbS + hw * 68 + c4) = v;
  }
  if (tid < 144) {
    wts[tid]       = w1h_g[tid];
    wts[144 + tid] = w1u_g[tid];
    wts[288 + tid] = w2h_g[tid];
    wts[432 + tid] = w2u_g[tid];
  }

  // ---- fm rows -> registers (2 per thread), straight from global (L2-hot) ----
  const int hC = tid / 50, ij2 = tid % 50, ij0 = ij2 * 2;
  float fmr0[64], fmr1[64];
  if (tid < 500) {
    const float* p0 = fm + n * 6400 + ij0 * 64;
#pragma unroll
    for (int c4 = 0; c4 < 16; ++c4) {
      float4 v0 = *(const float4*)(p0 + c4 * 4);
      float4 v1 = *(const float4*)(p0 + 64 + c4 * 4);
      fmr0[c4*4+0]=v0.x; fmr0[c4*4+1]=v0.y; fmr0[c4*4+2]=v0.z; fmr0[c4*4+3]=v0.w;
      fmr1[c4*4+0]=v1.x; fmr1[c4*4+1]=v1.y; fmr1[c4*4+2]=v1.z; fmr1[c4*4+3]=v1.w;
    }
  }
  __syncthreads();

  // ---- corr: xs[(ij*10+h)*12 + w] = dot64(fm[ij], fb[h*10+w]) ----
  if (tid < 500) {
    float a0[10], a1[10];
#pragma unroll
    for (int w = 0; w < 10; ++w) {
      const float* rw = fbS + (hC * 10 + w) * 68;
      float s0 = 0.f, s1 = 0.f;
#pragma unroll
      for (int c4 = 0; c4 < 16; ++c4) {
        float4 v = *(const float4*)(rw + c4 * 4);
        s0 += v.x*fmr0[4*c4] + v.y*fmr0[4*c4+1] + v.z*fmr0[4*c4+2] + v.w*fmr0[4*c4+3];
        s1 += v.x*fmr1[4*c4] + v.y*fmr1[4*c4+1] + v.z*fmr1[4*c4+2] + v.w*fmr1[4*c4+3];
      }
      a0[w] = s0; a1[w] = s1;
    }
    float* r0p = xs + (ij0 * 10 + hC) * 12;
    *(float4*)(r0p)     = make_float4(a0[0],a0[1],a0[2],a0[3]);
    *(float4*)(r0p + 4) = make_float4(a0[4],a0[5],a0[6],a0[7]);
    *(float4*)(r0p + 8) = make_float4(a0[8],a0[9],0.f,0.f);
    float* r1p = xs + ((ij0 + 1) * 10 + hC) * 12;
    *(float4*)(r1p)     = make_float4(a1[0],a1[1],a1[2],a1[3]);
    *(float4*)(r1p + 4) = make_float4(a1[4],a1[5],a1[6],a1[7]);
    *(float4*)(r1p + 8) = make_float4(a1[8],a1[9],0.f,0.f);
  }
  __syncthreads();

  // ---- conv: thread owns 2x2 (u,v) patch at fixed h; full x-neighborhood in regs
  const bool act = tid < 250;
  const int pu = tid / 50, prem = tid % 50, pv = prem / 10, h = prem % 10;
  const int u0 = pu * 2, v0 = pv * 2;

  float X[4][4][10];    // rows (u0-1+uu, v0-1+vv, h)
  float XH[2][4][10];   // rows (u0+i, v0+j, h -/+ 1)
  float acc[4][10];
  if (act) {
#pragma unroll
    for (int uu = 0; uu < 4; ++uu)
#pragma unroll
      for (int vv = 0; vv < 4; ++vv) {
        int up = u0 - 1 + uu, vp = v0 - 1 + vv;
        bool ok = (up >= 0) && (up < 10) && (vp >= 0) && (vp < 10);
        LOAD_ROW12(X[uu][vv], xs, ((up * 10 + vp) * 10 + h) * 12, ok);
      }
#pragma unroll
    for (int hh2 = 0; hh2 < 2; ++hh2) {
      int hh = h + (hh2 ? 1 : -1);
      bool okh = (hh >= 0) && (hh < 10);
#pragma unroll
      for (int i = 0; i < 2; ++i)
#pragma unroll
        for (int j = 0; j < 2; ++j) {
          LOAD_ROW12(XH[hh2][i*2+j], xs, (((u0+i)*10 + (v0+j))*10 + hh)*12, okh);
        }
    }
#pragma unroll
    for (int oi = 0; oi < 4; ++oi)
#pragma unroll
      for (int w = 0; w < 10; ++w) acc[oi][w] = 0.f;
  }

  for (int k = 0; k < 16; ++k) {
    float r1[4][10];
    if (act) {
      float wh[9], wu[9];
#pragma unroll
      for (int t = 0; t < 9; ++t) { wh[t] = wts[k*9+t]; wu[t] = wts[144 + k*9 + t]; }
      float o[4][10];
#pragma unroll
      for (int oi = 0; oi < 4; ++oi)
#pragma unroll
        for (int w = 0; w < 10; ++w) o[oi][w] = 0.f;
      // conv1 hw taps (all from registers)
#pragma unroll
      for (int i = 0; i < 2; ++i)
#pragma unroll
        for (int j = 0; j < 2; ++j) {
          int oi = i*2+j;
          HW_TAPS(o[oi], XH[0][oi],     wh[0], wh[1], wh[2]);
          HW_TAPS(o[oi], (X[1+i][1+j]), wh[3], wh[4], wh[5]);
          HW_TAPS(o[oi], XH[1][oi],     wh[6], wh[7], wh[8]);
        }
      // conv1 uv taps (all from registers)
#pragma unroll
      for (int uu = 0; uu < 4; ++uu)
#pragma unroll
        for (int vv = 0; vv < 4; ++vv) {
          UV_TAPS(o, (X[uu][vv]), wu);
        }
      // relu -> r1 regs + c1 LDS
#pragma unroll
      for (int i = 0; i < 2; ++i)
#pragma unroll
        for (int j = 0; j < 2; ++j) {
          int oi = i*2+j;
#pragma unroll
          for (int w = 0; w < 10; ++w) r1[oi][w] = fmaxf(o[oi][w], 0.f);
          float* cp = c1 + (((u0+i)*10 + (v0+j))*10 + h)*12;
          *(float4*)(cp)     = make_float4(r1[oi][0],r1[oi][1],r1[oi][2],r1[oi][3]);
          *(float4*)(cp + 4) = make_float4(r1[oi][4],r1[oi][5],r1[oi][6],r1[oi][7]);
          *(float4*)(cp + 8) = make_float4(r1[oi][8],r1[oi][9],0.f,0.f);
        }
    }
    __syncthreads();
    if (act) {
      float w2h_[9], w2u_[9];
#pragma unroll
      for (int t = 0; t < 9; ++t) { w2h_[t] = wts[288 + k*9 + t]; w2u_[t] = wts[432 + k*9 + t]; }
      // conv2 hw taps: center from r1 regs, h+-1 from LDS
#pragma unroll
      for (int i = 0; i < 2; ++i)
#pragma unroll
        for (int j = 0; j < 2; ++j) {
          int oi = i*2+j;
          HW_TAPS(acc[oi], r1[oi], w2h_[3], w2h_[4], w2h_[5]);
#pragma unroll
          for (int ky = 0; ky < 3; ky += 2) {
            int hh = h + ky - 1;
            bool okh = (hh >= 0) && (hh < 10);
            float R[10];
            LOAD_ROW12(R, c1, (((u0+i)*10 + (v0+j))*10 + hh)*12, okh);
            HW_TAPS(acc[oi], R, w2h_[ky*3], w2h_[ky*3+1], w2h_[ky*3+2]);
          }
        }
      // conv2 uv taps: own 4 rows from r1, 12 perimeter from LDS
#pragma unroll
      for (int uu = 0; uu < 4; ++uu)
#pragma unroll
        for (int vv = 0; vv < 4; ++vv) {
          float R[10];
          if (uu >= 1 && uu <= 2 && vv >= 1 && vv <= 2) {
#pragma unroll
            for (int w = 0; w < 10; ++w) R[w] = r1[(uu-1)*2 + (vv-1)][w];
          } else {
            int up = u0 - 1 + uu, vp = v0 - 1 + vv;
            bool ok = (up >= 0) && (up < 10) && (vp >= 0) && (vp < 10);
            LOAD_ROW12(R, c1, ((up*10 + vp)*10 + h)*12, ok);
          }
          UV_TAPS(acc, R, w2u_);
        }
    }
    __syncthreads();
  }

  // ---- attn: write conv output transposed T[hw][ij] into c1 region ----
  if (act) {
#pragma unroll
    for (int i = 0; i < 2; ++i)
#pragma unroll
      for (int j = 0; j < 2; ++j) {
        int ij = (u0 + i) * 10 + (v0 + j);
#pragma unroll
        for (int w = 0; w < 10; ++w) c1[(h*10 + w)*104 + ij] = acc[i*2+j][w];
      }
  }
  __syncthreads();
  // per-hw row: gaussian-normalize over ij (ddof=1), /5, softmax
  if (tid < 100) {
    float* row = c1 + tid * 104;
    float s = 0.f;
#pragma unroll
    for (int t4 = 0; t4 < 25; ++t4) {
      float4 v = *(const float4*)(row + t4*4);
      s += v.x + v.y + v.z + v.w;
    }
    float mean = s * 0.01f;
    float vs = 0.f, mx = -1e30f;
#pragma unroll
    for (int t4 = 0; t4 < 25; ++t4) {
      float4 v = *(const float4*)(row + t4*4);
      float d0 = v.x-mean, d1 = v.y-mean, d2 = v.z-mean, d3 = v.w-mean;
      vs += d0*d0 + d1*d1 + d2*d2 + d3*d3;
      mx = fmaxf(mx, fmaxf(fmaxf(d0,d1), fmaxf(d2,d3)));
    }
    float inv = 1.f / (5.f * sqrtf(vs * (1.f/99.f) + 1e-5f));
    float es = 0.f;
#pragma unroll
    for (int t4 = 0; t4 < 25; ++t4) {
      float4 v = *(const float4*)(row + t4*4);
      float4 e;
      e.x = expf((v.x - mean - mx) * inv);
      e.y = expf((v.y - mean - mx) * inv);
      e.z = expf((v.z - mean - mx) * inv);
      e.w = expf((v.w - mean - mx) * inv);
      es += e.x + e.y + e.z + e.w;
      *(float4*)(row + t4*4) = e;
    }
    rcps[tid] = 1.f / es;
  }
  __syncthreads();
  // attn[ij] = sum_hw p[hw][ij]
  if (tid < 100) {
    float s = 0.f;
    for (int hw = 0; hw < 100; ++hw) s += c1[hw*104 + tid] * rcps[hw];
    attn[q * 100 + tid] = s;
  }
}

// ---------------- att_mem[b,n,c] = sum_ij attn*feat_m / 100 ------------------
__global__ void k_attmem(const float* __restrict__ attn, const float* __restrict__ fmg,
                         float* __restrict__ am) {
  int q = blockIdx.x, n = q % 50;
  __shared__ float a[100];
  if (threadIdx.x < 100) a[threadIdx.x] = attn[q * 100 + threadIdx.x];
  __syncthreads();
  for (int c = threadIdx.x; c < 640; c += 256) {
    const float4* fp = (const float4*)(fmg + (n * 640 + c) * 100);
    float s = 0.f;
#pragma unroll
    for (int t4 = 0; t4 < 25; ++t4) {
      float4 v = fp[t4];
      s += a[t4*4]*v.x + a[t4*4+1]*v.y + a[t4*4+2]*v.z + a[t4*4+3]*v.w;
    }
    am[q * 640 + c] = s * 0.01f;
  }
}

// ---------------- encoder_output = spatial mean of feat_b --------------------
__global__ void k_enc(const float* __restrict__ fbg, float* __restrict__ enc) {
  int b = blockIdx.x;
  for (int c = threadIdx.x; c < 640; c += 256) {
    const float4* fp = (const float4*)(fbg + (b * 640 + c) * 100);
    float s = 0.f;
#pragma unroll
    for (int t4 = 0; t4 < 25; ++t4) {
      float4 v = fp[t4];
      s += v.x + v.y + v.z + v.w;
    }
    enc[b * 640 + c] = s * 0.01f;
  }
}

// ---------------- cosine sim + softmax over memory + mem_vec -----------------
__global__ void k_final1(const float* __restrict__ enc, const float* __restrict__ am,
                         float* __restrict__ mv) {
  int b = blockIdx.x, tid = threadIdx.x;
  __shared__ float e[640];
  __shared__ float wsm[50];
  __shared__ float wred[4];
  for (int c = tid; c < 640; c += 256) e[c] = enc[b * 640 + c];
  __syncthreads();
  float ps = 0.f;
  for (int c = tid; c < 640; c += 256) { float x = e[c]; ps += x * x; }
  for (int off = 32; off; off >>= 1) ps += __shfl_down(ps, off);
  if ((tid & 63) == 0) wred[tid >> 6] = ps;
  __syncthreads();
  float en = fmaxf(sqrtf(wred[0] + wred[1] + wred[2] + wred[3]), 1e-8f);
  if (tid < 50) {
    const float* ap = am + (b * 50 + tid) * 640;
    float dot = 0.f, nn = 0.f;
    for (int c = 0; c < 640; ++c) { float x = ap[c]; dot += x * e[c]; nn += x * x; }
    wsm[tid] = dot / (en * fmaxf(sqrtf(nn), 1e-8f));
  }
  __syncthreads();
  if (tid == 0) {
    float mx = -1e30f;
    for (int nn2 = 0; nn2 < 50; ++nn2) mx = fmaxf(mx, wsm[nn2]);
    float es = 0.f;
    for (int nn2 = 0; nn2 < 50; ++nn2) { float ex = expf(wsm[nn2] - mx); wsm[nn2] = ex; es += ex; }
    float rr = 1.f / es;
    for (int nn2 = 0; nn2 < 50; ++nn2) wsm[nn2] *= rr;
  }
  __syncthreads();
  for (int c = tid; c < 640; c += 256) {
    float s = 0.f;
    for (int nn2 = 0; nn2 < 50; ++nn2) s += wsm[nn2] * am[(b * 50 + nn2) * 640 + c];
    mv[b * 640 + c] = s;
  }
}

// ---------------- logits = concat(enc, mem_vec) @ W_fc + b_fc ----------------
__global__ void k_final2(const float* __restrict__ enc, const float* __restrict__ mv,
                         const float* __restrict__ Wfc, const float* __restrict__ bfc,
                         float* __restrict__ out) {
  int b = blockIdx.x >> 2, jc = blockIdx.x & 3;
  __shared__ float cat[1280];
  for (int c = threadIdx.x; c < 640; c += 256) {
    cat[c] = enc[b * 640 + c];
    cat[640 + c] = mv[b * 640 + c];
  }
  __syncthreads();
  if (threadIdx.x < 250) {
    int j = jc * 250 + threadIdx.x;
    float s = bfc[j];
    for (int c = 0; c < 1280; ++c) s += cat[c] * Wfc[c * 1000 + j];
    out[b * 1000 + j] = s;
  }
}

extern "C" void kernel_launch(void* const* d_in, const int* in_sizes, int n_in,
                              void* d_out, int out_size, void* d_ws, size_t ws_size,
                              hipStream_t stream) {
  const float* feat_b = (const float*)d_in[0];
  const float* feat_m = (const float*)d_in[1];
  const float* w1x1   = (const float*)d_in[2];
  const float* bns    = (const float*)d_in[3];
  const float* bnb    = (const float*)d_in[4];
  const float* w1h    = (const float*)d_in[5];
  const float* w1u    = (const float*)d_in[6];
  const float* w2h    = (const float*)d_in[7];
  const float* w2u    = (const float*)d_in[8];
  const float* Wfc    = (const float*)d_in[9];
  const float* bfc    = (const float*)d_in[10];
  float* ws = (float*)d_ws;
  float* wT   = ws + WS_WT;   float* wsum = ws + WS_WSUM;
  float* fbW  = ws + WS_FB;   float* fmW  = ws + WS_FM;
  float* attn = ws + WS_ATTN; float* am   = ws + WS_AM;
  float* enc  = ws + WS_ENC;  float* mv   = ws + WS_MV;

  k_prep  <<<161, 256, 0, stream>>>(w1x1, wT, wsum);
  k_embed <<<580,  64, 0, stream>>>(feat_b, feat_m, wT, wsum, bns, bnb, fbW, fmW);
  k_mid   <<<400, 512, 0, stream>>>(fbW, fmW, w1h, w1u, w2h, w2u, attn);
  k_attmem<<<400, 256, 0, stream>>>(attn, feat_m, am);
  k_enc   <<<8,   256, 0, stream>>>(feat_b, enc);
  k_final1<<<8,   256, 0, stream>>>(enc, am, mv);
  k_final2<<<32,  256, 0, stream>>>(enc, mv, Wfc, bfc, (float*)d_out);
}

// Round 3
// 926.708 us; speedup vs baseline: 1.9813x; 1.9813x over previous
//
#include <hip/hip_runtime.h>

// ---------------- workspace layout (floats) ----------------
#define WS_WT    0          // 640*64 transposed w1x1 [c][o]
#define WS_WSUM  40960      // 64 row sums of w1x1
#define WS_FB    41024      // 8*100*64   fb [b][hw][o]
#define WS_FM    92224      // 50*100*64  fm [n][ij][o]
#define WS_ATTN  412224     // 400*100 attn_memory [q][ij]
#define WS_AM    452224     // 8*50*640 att_mem [b][n][c]
#define WS_ENC   708224     // 8*640
#define WS_MV    713344     // 8*640

// ---------------- prep: transpose w1x1 + row sums ----------------
__global__ void k_prep(const float* __restrict__ w1x1, float* __restrict__ wT,
                       float* __restrict__ wsum) {
  if (blockIdx.x < 160) {
    int idx = blockIdx.x * 256 + threadIdx.x;   // < 40960
    int o = idx / 640, c = idx % 640;
    wT[c * 64 + o] = w1x1[idx];
  } else {
    int o = threadIdx.x;
    if (o < 64) {
      float s = 0.f;
      for (int c = 0; c < 640; ++c) s += w1x1[o * 640 + c];
      wsum[o] = s;
    }
  }
}

// ---------------- embed: mean-shift + 1x1 conv + BN + ReLU + L2 norm ----------
__global__ void k_embed(const float* __restrict__ fbg, const float* __restrict__ fmg,
                        const float* __restrict__ wT, const float* __restrict__ wsum,
                        const float* __restrict__ bns, const float* __restrict__ bnb,
                        float* __restrict__ fb, float* __restrict__ fm) {
  int lane = threadIdx.x;
  int pos0 = blockIdx.x * 10;
  const float* src; float* dst; int hw0;
  if (pos0 < 800) { int img = pos0 / 100; hw0 = pos0 % 100; src = fbg + img * 64000; dst = fb + pos0 * 64; }
  else { int p = pos0 - 800; int img = p / 100; hw0 = p % 100; src = fmg + img * 64000; dst = fm + p * 64; }

  __shared__ float xs[10][640];
  float lsum[10];
#pragma unroll
  for (int p = 0; p < 10; ++p) lsum[p] = 0.f;
  for (int i = 0; i < 10; ++i) {
    int c = lane + i * 64;
    const float* sp = src + c * 100 + hw0;
#pragma unroll
    for (int p = 0; p < 10; p += 2) {
      float2 v = *(const float2*)(sp + p);
      xs[p][c] = v.x; xs[p + 1][c] = v.y;
      lsum[p] += v.x; lsum[p + 1] += v.y;
    }
  }
  float mean[10];
#pragma unroll
  for (int p = 0; p < 10; ++p) {
    float s = lsum[p];
    for (int off = 32; off; off >>= 1) s += __shfl_down(s, off);
    mean[p] = __shfl(s, 0) * (1.f / 640.f);
  }
  __syncthreads();
  float acc[10];
#pragma unroll
  for (int p = 0; p < 10; ++p) acc[p] = 0.f;
  for (int c = 0; c < 640; ++c) {
    float w = wT[c * 64 + lane];
#pragma unroll
    for (int p = 0; p < 10; ++p) acc[p] += xs[p][c] * w;
  }
  float wsl = wsum[lane], sc = bns[lane], bi = bnb[lane];
#pragma unroll
  for (int p = 0; p < 10; ++p) {
    float y = (acc[p] - mean[p] * wsl) * sc + bi;
    y = fmaxf(y, 0.f);
    float sq = y * y;
    for (int off = 32; off; off >>= 1) sq += __shfl_down(sq, off);
    float nrm = sqrtf(__shfl(sq, 0));
    dst[p * 64 + lane] = y / fmaxf(nrm, 1e-8f);
  }
}

// ================= fused corr + sep-conv4d(x2) + attn-softmax ================
// 512 threads, __launch_bounds__(512,2) -> 256-VGPR budget, 8 waves/CU.
// Thread t<500 owns a v-pair: rows (u, v0, h) and (u, v0+1, h), 10 w each.
// Register tile: 16 k-invariant x-rows (160 f). Weights via wave-uniform
// global loads (s_load path, no LDS cost). LDS rows stride 12 (b128-aligned).

#define LOAD_ROW12(DST, BASE, OFFW, OK) {                                   \
    int _o = (OK) ? (OFFW) : 0;                                             \
    float4 _a = *(const float4*)((BASE) + _o);                              \
    float4 _b = *(const float4*)((BASE) + _o + 4);                          \
    float4 _c = *(const float4*)((BASE) + _o + 8);                          \
    if (!(OK)) { _a = make_float4(0,0,0,0); _b = _a; _c = _a; }             \
    DST[0]=_a.x; DST[1]=_a.y; DST[2]=_a.z; DST[3]=_a.w;                     \
    DST[4]=_b.x; DST[5]=_b.y; DST[6]=_b.z; DST[7]=_b.w;                     \
    DST[8]=_c.x; DST[9]=_c.y; }

#define HW_TAPS(OUT, ROW, W0, W1, W2) {                                     \
    _Pragma("unroll") for (int w = 1; w < 10; ++w) OUT[w] += (W0)*ROW[w-1]; \
    _Pragma("unroll") for (int w = 0; w < 10; ++w) OUT[w] += (W1)*ROW[w];   \
    _Pragma("unroll") for (int w = 0; w < 9;  ++w) OUT[w] += (W2)*ROW[w+1]; }

__global__ __launch_bounds__(512, 2) void k_mid(
    const float* __restrict__ fb, const float* __restrict__ fm,
    const float* __restrict__ w1h_g, const float* __restrict__ w1u_g,
    const float* __restrict__ w2h_g, const float* __restrict__ w2u_g,
    float* __restrict__ attn)
{
  __shared__ float xs[12000];    // corr rows (ij*10+h) stride 12
  __shared__ float c1[12000];    // per-k hidden; later reused as T[100][104]
  __shared__ float fbS[6800];    // fb rows stride 68 (17 float4s)
  __shared__ float rcps[100];
  const int tid = threadIdx.x, q = blockIdx.x;
  const int b = q / 50, n = q % 50;

  const bool act = tid < 500;
  const int u = tid / 50, rem = tid % 50, v0 = (rem / 10) * 2, h = rem % 10;
  const int ij0 = u * 10 + v0;

  // ---- stage fb rows ----
  for (int i = tid; i < 1600; i += 512) {
    int hw = i >> 4, c4 = (i & 15) << 2;
    *(float4*)(fbS + hw * 68 + c4) = *(const float4*)(fb + b * 6400 + hw * 64 + c4);
  }

  // ---- corr phase: fm rows (2) in regs, fb rows from LDS ----
  {
    float fm0[64], fm1[64];
    if (act) {
      const float* p0 = fm + n * 6400 + ij0 * 64;
#pragma unroll
      for (int c4 = 0; c4 < 16; ++c4) {
        float4 v0d = *(const float4*)(p0 + c4 * 4);
        float4 v1d = *(const float4*)(p0 + 64 + c4 * 4);
        fm0[c4*4+0]=v0d.x; fm0[c4*4+1]=v0d.y; fm0[c4*4+2]=v0d.z; fm0[c4*4+3]=v0d.w;
        fm1[c4*4+0]=v1d.x; fm1[c4*4+1]=v1d.y; fm1[c4*4+2]=v1d.z; fm1[c4*4+3]=v1d.w;
      }
    }
    __syncthreads();           // fbS ready
    if (act) {
#pragma unroll
      for (int w = 0; w < 10; ++w) {
        const float* rw = fbS + (h * 10 + w) * 68;
        float s0 = 0.f, s1 = 0.f;
#pragma unroll
        for (int c4 = 0; c4 < 16; ++c4) {
          float4 v = *(const float4*)(rw + c4 * 4);
          s0 += v.x*fm0[4*c4] + v.y*fm0[4*c4+1] + v.z*fm0[4*c4+2] + v.w*fm0[4*c4+3];
          s1 += v.x*fm1[4*c4] + v.y*fm1[4*c4+1] + v.z*fm1[4*c4+2] + v.w*fm1[4*c4+3];
        }
        xs[(ij0 * 10 + h) * 12 + w]       = s0;
        xs[((ij0 + 1) * 10 + h) * 12 + w] = s1;
      }
    }
  }
  __syncthreads();             // xs (corr) ready

  // ---- conv phase: cache 16 x-rows in regs (k-invariant) ----
  float X[3][4][10];   // uv grid: (u-1+du, v0-1+dv, h)
  float XH[2][2][10];  // (u, v0+j, h -/+ 1)
  float acc[2][10];
  if (act) {
#pragma unroll
    for (int du = 0; du < 3; ++du)
#pragma unroll
      for (int dvv = 0; dvv < 4; ++dvv) {
        int up = u - 1 + du, vp = v0 - 1 + dvv;
        bool ok = (up >= 0) && (up < 10) && (vp >= 0) && (vp < 10);
        LOAD_ROW12(X[du][dvv], xs, ((up * 10 + vp) * 10 + h) * 12, ok);
      }
#pragma unroll
    for (int j = 0; j < 2; ++j)
#pragma unroll
      for (int s = 0; s < 2; ++s) {
        int hh = h + (s ? 1 : -1);
        bool okh = (hh >= 0) && (hh < 10);
        LOAD_ROW12(XH[j][s], xs, ((ij0 + j) * 10 + hh) * 12, okh);
      }
#pragma unroll
    for (int j = 0; j < 2; ++j)
#pragma unroll
      for (int w = 0; w < 10; ++w) acc[j][w] = 0.f;
  }

  for (int k = 0; k < 16; ++k) {
    // weights: wave-uniform global reads -> scalar loads (no LDS traffic)
    float whA[9], wuA[9], w2hA[9], w2uA[9];
#pragma unroll
    for (int t = 0; t < 9; ++t) {
      whA[t]  = w1h_g[k * 9 + t];
      wuA[t]  = w1u_g[k * 9 + t];
      w2hA[t] = w2h_g[k * 9 + t];
      w2uA[t] = w2u_g[k * 9 + t];
    }
    float r1[2][10];
    if (act) {
      float o[2][10];
#pragma unroll
      for (int j = 0; j < 2; ++j)
#pragma unroll
        for (int w = 0; w < 10; ++w) o[j][w] = 0.f;
      // conv1 hw taps (regs)
#pragma unroll
      for (int j = 0; j < 2; ++j) {
        HW_TAPS(o[j], XH[j][0],    whA[0], whA[1], whA[2]);
        HW_TAPS(o[j], X[1][j + 1], whA[3], whA[4], whA[5]);
        HW_TAPS(o[j], XH[j][1],    whA[6], whA[7], whA[8]);
      }
      // conv1 uv taps (regs)
#pragma unroll
      for (int j = 0; j < 2; ++j)
#pragma unroll
        for (int du = 0; du < 3; ++du)
#pragma unroll
          for (int dv = 0; dv < 3; ++dv) {
            float wgt = wuA[du * 3 + dv];
#pragma unroll
            for (int w = 0; w < 10; ++w) o[j][w] += wgt * X[du][j + dv][w];
          }
      // relu -> r1 regs + c1 LDS
#pragma unroll
      for (int j = 0; j < 2; ++j) {
#pragma unroll
        for (int w = 0; w < 10; ++w) r1[j][w] = fmaxf(o[j][w], 0.f);
        float* cp = c1 + ((ij0 + j) * 10 + h) * 12;
        *(float4*)(cp)     = make_float4(r1[j][0], r1[j][1], r1[j][2], r1[j][3]);
        *(float4*)(cp + 4) = make_float4(r1[j][4], r1[j][5], r1[j][6], r1[j][7]);
        *(float4*)(cp + 8) = make_float4(r1[j][8], r1[j][9], 0.f, 0.f);
      }
    }
    __syncthreads();
    if (act) {
      // conv2 hw taps: center from r1, h+-1 from LDS
#pragma unroll
      for (int j = 0; j < 2; ++j) {
        HW_TAPS(acc[j], r1[j], w2hA[3], w2hA[4], w2hA[5]);
#pragma unroll
        for (int s = 0; s < 2; ++s) {
          int hh = h + (s ? 1 : -1);
          bool okh = (hh >= 0) && (hh < 10);
          float R[10];
          LOAD_ROW12(R, c1, ((ij0 + j) * 10 + hh) * 12, okh);
          int t0 = s ? 6 : 0;
          HW_TAPS(acc[j], R, w2hA[t0], w2hA[t0 + 1], w2hA[t0 + 2]);
        }
      }
      // conv2 uv taps: 2 center rows from r1, 10 from LDS
#pragma unroll
      for (int du = 0; du < 3; ++du)
#pragma unroll
        for (int dvv = 0; dvv < 4; ++dvv) {
          float R[10];
          if (du == 1 && (dvv == 1 || dvv == 2)) {
#pragma unroll
            for (int w = 0; w < 10; ++w) R[w] = r1[dvv - 1][w];
          } else {
            int up = u - 1 + du, vp = v0 - 1 + dvv;
            bool ok = (up >= 0) && (up < 10) && (vp >= 0) && (vp < 10);
            LOAD_ROW12(R, c1, ((up * 10 + vp) * 10 + h) * 12, ok);
          }
#pragma unroll
          for (int j = 0; j < 2; ++j) {
            int t = dvv - j;
            if (t >= 0 && t < 3) {
              float wgt = w2uA[du * 3 + t];
#pragma unroll
              for (int w = 0; w < 10; ++w) acc[j][w] += wgt * R[w];
            }
          }
        }
    }
    __syncthreads();
  }

  // ---- attn: transpose conv output into c1 as T[hw][ij] (stride 104) ----
  if (act) {
#pragma unroll
    for (int j = 0; j < 2; ++j)
#pragma unroll
      for (int w = 0; w < 10; ++w) c1[(h * 10 + w) * 104 + ij0 + j] = acc[j][w];
  }
  __syncthreads();
  // per-hw row: gaussian-normalize over ij (ddof=1), /5, softmax
  if (tid < 100) {
    float* row = c1 + tid * 104;
    float s = 0.f;
#pragma unroll
    for (int t4 = 0; t4 < 25; ++t4) {
      float4 v = *(const float4*)(row + t4 * 4);
      s += v.x + v.y + v.z + v.w;
    }
    float mean = s * 0.01f;
    float vs = 0.f, mx = -1e30f;
#pragma unroll
    for (int t4 = 0; t4 < 25; ++t4) {
      float4 v = *(const float4*)(row + t4 * 4);
      float d0 = v.x-mean, d1 = v.y-mean, d2 = v.z-mean, d3 = v.w-mean;
      vs += d0*d0 + d1*d1 + d2*d2 + d3*d3;
      mx = fmaxf(mx, fmaxf(fmaxf(d0, d1), fmaxf(d2, d3)));
    }
    float inv = 1.f / (5.f * sqrtf(vs * (1.f / 99.f) + 1e-5f));
    float es = 0.f;
#pragma unroll
    for (int t4 = 0; t4 < 25; ++t4) {
      float4 v = *(const float4*)(row + t4 * 4);
      float4 e;
      e.x = expf((v.x - mean - mx) * inv);
      e.y = expf((v.y - mean - mx) * inv);
      e.z = expf((v.z - mean - mx) * inv);
      e.w = expf((v.w - mean - mx) * inv);
      es += e.x + e.y + e.z + e.w;
      *(float4*)(row + t4 * 4) = e;
    }
    rcps[tid] = 1.f / es;
  }
  __syncthreads();
  // attn[ij] = sum_hw p[hw][ij]
  if (tid < 100) {
    float s = 0.f;
    for (int hw = 0; hw < 100; ++hw) s += c1[hw * 104 + tid] * rcps[hw];
    attn[q * 100 + tid] = s;
  }
}

// ---------------- att_mem[b,n,c] = sum_ij attn*feat_m / 100 ------------------
__global__ void k_attmem(const float* __restrict__ attn, const float* __restrict__ fmg,
                         float* __restrict__ am) {
  int q = blockIdx.x, n = q % 50;
  __shared__ float a[100];
  if (threadIdx.x < 100) a[threadIdx.x] = attn[q * 100 + threadIdx.x];
  __syncthreads();
  for (int c = threadIdx.x; c < 640; c += 256) {
    const float4* fp = (const float4*)(fmg + (n * 640 + c) * 100);
    float s = 0.f;
#pragma unroll
    for (int t4 = 0; t4 < 25; ++t4) {
      float4 v = fp[t4];
      s += a[t4*4]*v.x + a[t4*4+1]*v.y + a[t4*4+2]*v.z + a[t4*4+3]*v.w;
    }
    am[q * 640 + c] = s * 0.01f;
  }
}

// ---------------- encoder_output = spatial mean of feat_b --------------------
__global__ void k_enc(const float* __restrict__ fbg, float* __restrict__ enc) {
  int b = blockIdx.x;
  for (int c = threadIdx.x; c < 640; c += 256) {
    const float4* fp = (const float4*)(fbg + (b * 640 + c) * 100);
    float s = 0.f;
#pragma unroll
    for (int t4 = 0; t4 < 25; ++t4) {
      float4 v = fp[t4];
      s += v.x + v.y + v.z + v.w;
    }
    enc[b * 640 + c] = s * 0.01f;
  }
}

// ---------------- cosine sim + softmax over memory + mem_vec -----------------
__global__ void k_final1(const float* __restrict__ enc, const float* __restrict__ am,
                         float* __restrict__ mv) {
  int b = blockIdx.x, tid = threadIdx.x;
  __shared__ float e[640];
  __shared__ float wsm[50];
  __shared__ float wred[4];
  for (int c = tid; c < 640; c += 256) e[c] = enc[b * 640 + c];
  __syncthreads();
  float ps = 0.f;
  for (int c = tid; c < 640; c += 256) { float x = e[c]; ps += x * x; }
  for (int off = 32; off; off >>= 1) ps += __shfl_down(ps, off);
  if ((tid & 63) == 0) wred[tid >> 6] = ps;
  __syncthreads();
  float en = fmaxf(sqrtf(wred[0] + wred[1] + wred[2] + wred[3]), 1e-8f);
  if (tid < 50) {
    const float* ap = am + (b * 50 + tid) * 640;
    float dot = 0.f, nn = 0.f;
    for (int c = 0; c < 640; ++c) { float x = ap[c]; dot += x * e[c]; nn += x * x; }
    wsm[tid] = dot / (en * fmaxf(sqrtf(nn), 1e-8f));
  }
  __syncthreads();
  if (tid == 0) {
    float mx = -1e30f;
    for (int nn2 = 0; nn2 < 50; ++nn2) mx = fmaxf(mx, wsm[nn2]);
    float es = 0.f;
    for (int nn2 = 0; nn2 < 50; ++nn2) { float ex = expf(wsm[nn2] - mx); wsm[nn2] = ex; es += ex; }
    float rr = 1.f / es;
    for (int nn2 = 0; nn2 < 50; ++nn2) wsm[nn2] *= rr;
  }
  __syncthreads();
  for (int c = tid; c < 640; c += 256) {
    float s = 0.f;
    for (int nn2 = 0; nn2 < 50; ++nn2) s += wsm[nn2] * am[(b * 50 + nn2) * 640 + c];
    mv[b * 640 + c] = s;
  }
}

// ---------------- logits = concat(enc, mem_vec) @ W_fc + b_fc ----------------
__global__ void k_final2(const float* __restrict__ enc, const float* __restrict__ mv,
                         const float* __restrict__ Wfc, const float* __restrict__ bfc,
                         float* __restrict__ out) {
  int b = blockIdx.x >> 2, jc = blockIdx.x & 3;
  __shared__ float cat[1280];
  for (int c = threadIdx.x; c < 640; c += 256) {
    cat[c] = enc[b * 640 + c];
    cat[640 + c] = mv[b * 640 + c];
  }
  __syncthreads();
  if (threadIdx.x < 250) {
    int j = jc * 250 + threadIdx.x;
    float s = bfc[j];
    for (int c = 0; c < 1280; ++c) s += cat[c] * Wfc[c * 1000 + j];
    out[b * 1000 + j] = s;
  }
}

extern "C" void kernel_launch(void* const* d_in, const int* in_sizes, int n_in,
                              void* d_out, int out_size, void* d_ws, size_t ws_size,
                              hipStream_t stream) {
  const float* feat_b = (const float*)d_in[0];
  const float* feat_m = (const float*)d_in[1];
  const float* w1x1   = (const float*)d_in[2];
  const float* bns    = (const float*)d_in[3];
  const float* bnb    = (const float*)d_in[4];
  const float* w1h    = (const float*)d_in[5];
  const float* w1u    = (const float*)d_in[6];
  const float* w2h    = (const float*)d_in[7];
  const float* w2u    = (const float*)d_in[8];
  const float* Wfc    = (const float*)d_in[9];
  const float* bfc    = (const float*)d_in[10];
  float* ws = (float*)d_ws;
  float* wT   = ws + WS_WT;   float* wsum = ws + WS_WSUM;
  float* fbW  = ws + WS_FB;   float* fmW  = ws + WS_FM;
  float* attn = ws + WS_ATTN; float* am   = ws + WS_AM;
  float* enc  = ws + WS_ENC;  float* mv   = ws + WS_MV;

  k_prep  <<<161, 256, 0, stream>>>(w1x1, wT, wsum);
  k_embed <<<580,  64, 0, stream>>>(feat_b, feat_m, wT, wsum, bns, bnb, fbW, fmW);
  k_mid   <<<400, 512, 0, stream>>>(fbW, fmW, w1h, w1u, w2h, w2u, attn);
  k_attmem<<<400, 256, 0, stream>>>(attn, feat_m, am);
  k_enc   <<<8,   256, 0, stream>>>(feat_b, enc);
  k_final1<<<8,   256, 0, stream>>>(enc, am, mv);
  k_final2<<<32,  256, 0, stream>>>(enc, mv, Wfc, bfc, (float*)d_out);
}

// Round 4
// 603.488 us; speedup vs baseline: 3.0424x; 1.5356x over previous
//
#include <hip/hip_runtime.h>

// ---------------- workspace layout (floats) ----------------
#define WS_FB    0          // 8*100*64   fb [b][hw][o]
#define WS_FM    51200      // 50*100*64  fm [n][ij][o]
#define WS_ATTN  371200     // 400*100 attn_memory [q][ij]
#define WS_AM    411200     // 8*50*640 att_mem [b][n][c]
#define WS_ENC   667200     // 8*640
// total ~672K floats = 2.7 MB

// ---------------- embed: mean-shift + 1x1 conv + BN + ReLU + L2 norm ----------
// 580 blocks x 64 threads (1 wave). lane = output channel o.
// w1x1 row per lane read directly from global (L2-resident), wsum computed inline.
__global__ void k_embed(const float* __restrict__ fbg, const float* __restrict__ fmg,
                        const float* __restrict__ w1x1,
                        const float* __restrict__ bns, const float* __restrict__ bnb,
                        float* __restrict__ fb, float* __restrict__ fm) {
  int lane = threadIdx.x;
  int pos0 = blockIdx.x * 10;
  const float* src; float* dst; int hw0;
  if (pos0 < 800) { int img = pos0 / 100; hw0 = pos0 % 100; src = fbg + img * 64000; dst = fb + pos0 * 64; }
  else { int p = pos0 - 800; int img = p / 100; hw0 = p % 100; src = fmg + img * 64000; dst = fm + p * 64; }

  __shared__ float xs[10][640];
  float lsum[10];
#pragma unroll
  for (int p = 0; p < 10; ++p) lsum[p] = 0.f;
  for (int i = 0; i < 10; ++i) {
    int c = lane + i * 64;
    const float* sp = src + c * 100 + hw0;
#pragma unroll
    for (int p = 0; p < 10; p += 2) {
      float2 v = *(const float2*)(sp + p);
      xs[p][c] = v.x; xs[p + 1][c] = v.y;
      lsum[p] += v.x; lsum[p + 1] += v.y;
    }
  }
  float mean[10];
#pragma unroll
  for (int p = 0; p < 10; ++p) {
    float s = lsum[p];
    for (int off = 32; off; off >>= 1) s += __shfl_down(s, off);
    mean[p] = __shfl(s, 0) * (1.f / 640.f);
  }
  __syncthreads();
  float acc[10];
#pragma unroll
  for (int p = 0; p < 10; ++p) acc[p] = 0.f;
  float wsl = 0.f;
  const float* wrow = w1x1 + lane * 640;
  for (int c4 = 0; c4 < 160; ++c4) {
    float4 w4 = *(const float4*)(wrow + c4 * 4);
    wsl += w4.x + w4.y + w4.z + w4.w;
#pragma unroll
    for (int p = 0; p < 10; ++p) {
      float4 x4 = *(const float4*)(&xs[p][c4 * 4]);   // wave-broadcast b128
      acc[p] += w4.x * x4.x + w4.y * x4.y + w4.z * x4.z + w4.w * x4.w;
    }
  }
  float sc = bns[lane], bi = bnb[lane];
#pragma unroll
  for (int p = 0; p < 10; ++p) {
    float y = (acc[p] - mean[p] * wsl) * sc + bi;
    y = fmaxf(y, 0.f);
    float sq = y * y;
    for (int off = 32; off; off >>= 1) sq += __shfl_down(sq, off);
    float nrm = sqrtf(__shfl(sq, 0));
    dst[p * 64 + lane] = y / fmaxf(nrm, 1e-8f);
  }
}

// ================= fused corr + sep-conv4d(x2) + attn-softmax ================
// 256 threads, __launch_bounds__(256,1): 4 waves/CU, VGPR budget ~512 (no spill <450).
// Thread t<250 owns a 2x2 uv patch at fixed h: rows (2pu+i, 2pv+j, h).
// Full x-neighborhood (16 uv rows + 8 h-neighbor rows) register-cached, k-invariant.

#define LOAD_ROW12(DST, BASE, OFFW, OK) {                                   \
    int _o = (OK) ? (OFFW) : 0;                                             \
    float4 _a = *(const float4*)((BASE) + _o);                              \
    float4 _b = *(const float4*)((BASE) + _o + 4);                          \
    float4 _c = *(const float4*)((BASE) + _o + 8);                          \
    if (!(OK)) { _a = make_float4(0,0,0,0); _b = _a; _c = _a; }             \
    DST[0]=_a.x; DST[1]=_a.y; DST[2]=_a.z; DST[3]=_a.w;                     \
    DST[4]=_b.x; DST[5]=_b.y; DST[6]=_b.z; DST[7]=_b.w;                     \
    DST[8]=_c.x; DST[9]=_c.y; }

#define HW_TAPS(OUT, ROW, W0, W1, W2) {                                     \
    _Pragma("unroll") for (int w = 1; w < 10; ++w) OUT[w] += (W0)*ROW[w-1]; \
    _Pragma("unroll") for (int w = 0; w < 10; ++w) OUT[w] += (W1)*ROW[w];   \
    _Pragma("unroll") for (int w = 0; w < 9;  ++w) OUT[w] += (W2)*ROW[w+1]; }

#define UV_TAPS(ACCARR, ROW, WARR) {                                        \
    _Pragma("unroll") for (int i = 0; i < 2; ++i) {                         \
      _Pragma("unroll") for (int j = 0; j < 2; ++j) {                       \
        int du = uu - 1 - i, dv = vv - 1 - j;                               \
        if (du >= -1 && du <= 1 && dv >= -1 && dv <= 1) {                   \
          float wgt = WARR[(du+1)*3 + (dv+1)];                              \
          _Pragma("unroll") for (int w = 0; w < 10; ++w)                    \
            ACCARR[i*2+j][w] += wgt * ROW[w];                               \
        } } } }

__global__ __launch_bounds__(256, 1) void k_mid(
    const float* __restrict__ fb, const float* __restrict__ fm,
    const float* __restrict__ w1h_g, const float* __restrict__ w1u_g,
    const float* __restrict__ w2h_g, const float* __restrict__ w2u_g,
    float* __restrict__ attn)
{
  __shared__ float xs[12000];    // corr rows (ij*10+h), stride 12
  __shared__ float c1[12000];    // per-k hidden; later reused as T[100][100]
  __shared__ float fbS[6800];    // fb rows, stride 68
  __shared__ float rcps[100];
  const int tid = threadIdx.x, q = blockIdx.x;
  const int b = q / 50, n = q % 50;

  const bool act = tid < 250;
  const int pu = tid / 50, prem = tid % 50, pv = prem / 10, h = prem % 10;
  const int u0 = pu * 2, v0 = pv * 2;
  const int ij0 = u0 * 10 + v0;

  // ---- stage fb rows ----
  for (int i = tid; i < 1600; i += 256) {
    int hw = i >> 4, c4 = (i & 15) << 2;
    *(float4*)(fbS + hw * 68 + c4) = *(const float4*)(fb + b * 6400 + hw * 64 + c4);
  }
  __syncthreads();

  // ---- corr: 2 passes, each computes 2 ij rows (fm pair in regs) ----
#pragma unroll 1
  for (int pass = 0; pass < 2; ++pass) {
    if (act) {
      int ijb = ij0 + pass * 10;
      float fmA[64], fmB[64];
      const float* p0 = fm + n * 6400 + ijb * 64;
#pragma unroll
      for (int c4 = 0; c4 < 16; ++c4) {
        float4 vA = *(const float4*)(p0 + c4 * 4);
        float4 vB = *(const float4*)(p0 + 64 + c4 * 4);
        fmA[c4*4+0]=vA.x; fmA[c4*4+1]=vA.y; fmA[c4*4+2]=vA.z; fmA[c4*4+3]=vA.w;
        fmB[c4*4+0]=vB.x; fmB[c4*4+1]=vB.y; fmB[c4*4+2]=vB.z; fmB[c4*4+3]=vB.w;
      }
      float a0[10], a1[10];
#pragma unroll
      for (int w = 0; w < 10; ++w) {
        const float* rw = fbS + (h * 10 + w) * 68;
        float s0 = 0.f, s1 = 0.f;
#pragma unroll
        for (int c4 = 0; c4 < 16; ++c4) {
          float4 v = *(const float4*)(rw + c4 * 4);
          s0 += v.x*fmA[4*c4] + v.y*fmA[4*c4+1] + v.z*fmA[4*c4+2] + v.w*fmA[4*c4+3];
          s1 += v.x*fmB[4*c4] + v.y*fmB[4*c4+1] + v.z*fmB[4*c4+2] + v.w*fmB[4*c4+3];
        }
        a0[w] = s0; a1[w] = s1;
      }
      float* r0p = xs + (ijb * 10 + h) * 12;
      *(float4*)(r0p)     = make_float4(a0[0],a0[1],a0[2],a0[3]);
      *(float4*)(r0p + 4) = make_float4(a0[4],a0[5],a0[6],a0[7]);
      *(float4*)(r0p + 8) = make_float4(a0[8],a0[9],0.f,0.f);
      float* r1p = xs + ((ijb + 1) * 10 + h) * 12;
      *(float4*)(r1p)     = make_float4(a1[0],a1[1],a1[2],a1[3]);
      *(float4*)(r1p + 4) = make_float4(a1[4],a1[5],a1[6],a1[7]);
      *(float4*)(r1p + 8) = make_float4(a1[8],a1[9],0.f,0.f);
    }
  }
  __syncthreads();             // xs (corr) ready

  // ---- conv: cache full x-neighborhood in regs (k-invariant) ----
  float X[4][4][10];    // (u0-1+uu, v0-1+vv, h)
  float XH[2][4][10];   // (u0+i, v0+j, h -/+ 1)
  float acc[4][10];
  if (act) {
#pragma unroll
    for (int uu = 0; uu < 4; ++uu)
#pragma unroll
      for (int vv = 0; vv < 4; ++vv) {
        int up = u0 - 1 + uu, vp = v0 - 1 + vv;
        bool ok = (up >= 0) && (up < 10) && (vp >= 0) && (vp < 10);
        LOAD_ROW12(X[uu][vv], xs, ((up * 10 + vp) * 10 + h) * 12, ok);
      }
#pragma unroll
    for (int hh2 = 0; hh2 < 2; ++hh2) {
      int hh = h + (hh2 ? 1 : -1);
      bool okh = (hh >= 0) && (hh < 10);
#pragma unroll
      for (int i = 0; i < 2; ++i)
#pragma unroll
        for (int j = 0; j < 2; ++j) {
          LOAD_ROW12(XH[hh2][i*2+j], xs, (((u0+i)*10 + (v0+j))*10 + hh)*12, okh);
        }
    }
#pragma unroll
    for (int oi = 0; oi < 4; ++oi)
#pragma unroll
      for (int w = 0; w < 10; ++w) acc[oi][w] = 0.f;
  }

  for (int k = 0; k < 16; ++k) {
    // conv1 weights: wave-uniform global reads -> scalar loads
    float wA[9], wB[9];
#pragma unroll
    for (int t = 0; t < 9; ++t) { wA[t] = w1h_g[k * 9 + t]; wB[t] = w1u_g[k * 9 + t]; }
    float r1[4][10];
    if (act) {
      float o[4][10];
#pragma unroll
      for (int oi = 0; oi < 4; ++oi)
#pragma unroll
        for (int w = 0; w < 10; ++w) o[oi][w] = 0.f;
      // conv1 hw taps (regs)
#pragma unroll
      for (int i = 0; i < 2; ++i)
#pragma unroll
        for (int j = 0; j < 2; ++j) {
          int oi = i*2+j;
          HW_TAPS(o[oi], XH[0][oi],     wA[0], wA[1], wA[2]);
          HW_TAPS(o[oi], (X[1+i][1+j]), wA[3], wA[4], wA[5]);
          HW_TAPS(o[oi], XH[1][oi],     wA[6], wA[7], wA[8]);
        }
      // conv1 uv taps (regs)
#pragma unroll
      for (int uu = 0; uu < 4; ++uu)
#pragma unroll
        for (int vv = 0; vv < 4; ++vv) {
          UV_TAPS(o, (X[uu][vv]), wB);
        }
      // relu -> r1 regs + c1 LDS
#pragma unroll
      for (int i = 0; i < 2; ++i)
#pragma unroll
        for (int j = 0; j < 2; ++j) {
          int oi = i*2+j;
#pragma unroll
          for (int w = 0; w < 10; ++w) r1[oi][w] = fmaxf(o[oi][w], 0.f);
          float* cp = c1 + (((u0+i)*10 + (v0+j))*10 + h)*12;
          *(float4*)(cp)     = make_float4(r1[oi][0],r1[oi][1],r1[oi][2],r1[oi][3]);
          *(float4*)(cp + 4) = make_float4(r1[oi][4],r1[oi][5],r1[oi][6],r1[oi][7]);
          *(float4*)(cp + 8) = make_float4(r1[oi][8],r1[oi][9],0.f,0.f);
        }
    }
    __syncthreads();
    // conv2 weights (reuse wA/wB regs)
#pragma unroll
    for (int t = 0; t < 9; ++t) { wA[t] = w2h_g[k * 9 + t]; wB[t] = w2u_g[k * 9 + t]; }
    if (act) {
      // conv2 hw taps: center from r1, h+-1 from LDS
#pragma unroll
      for (int i = 0; i < 2; ++i)
#pragma unroll
        for (int j = 0; j < 2; ++j) {
          int oi = i*2+j;
          HW_TAPS(acc[oi], r1[oi], wA[3], wA[4], wA[5]);
#pragma unroll
          for (int ky = 0; ky < 3; ky += 2) {
            int hh = h + ky - 1;
            bool okh = (hh >= 0) && (hh < 10);
            float R[10];
            LOAD_ROW12(R, c1, (((u0+i)*10 + (v0+j))*10 + hh)*12, okh);
            HW_TAPS(acc[oi], R, wA[ky*3], wA[ky*3+1], wA[ky*3+2]);
          }
        }
      // conv2 uv taps: own 4 rows from r1, 12 perimeter from LDS
#pragma unroll
      for (int uu = 0; uu < 4; ++uu)
#pragma unroll
        for (int vv = 0; vv < 4; ++vv) {
          float R[10];
          if (uu >= 1 && uu <= 2 && vv >= 1 && vv <= 2) {
#pragma unroll
            for (int w = 0; w < 10; ++w) R[w] = r1[(uu-1)*2 + (vv-1)][w];
          } else {
            int up = u0 - 1 + uu, vp = v0 - 1 + vv;
            bool ok = (up >= 0) && (up < 10) && (vp >= 0) && (vp < 10);
            LOAD_ROW12(R, c1, ((up*10 + vp)*10 + h)*12, ok);
          }
          UV_TAPS(acc, R, wB);
        }
    }
    __syncthreads();
  }

  // ---- attn: write conv output transposed T[hw][ij] (stride 100) ----
  if (act) {
#pragma unroll
    for (int i = 0; i < 2; ++i)
#pragma unroll
      for (int j = 0; j < 2; ++j) {
        int ij = (u0 + i) * 10 + (v0 + j);
#pragma unroll
        for (int w = 0; w < 10; ++w) c1[(h*10 + w)*100 + ij] = acc[i*2+j][w];
      }
  }
  __syncthreads();
  // per-hw row: gaussian-normalize over ij (ddof=1), /5, softmax
  if (tid < 100) {
    float* row = c1 + tid * 100;
    float s = 0.f;
#pragma unroll
    for (int t4 = 0; t4 < 25; ++t4) {
      float4 v = *(const float4*)(row + t4 * 4);
      s += v.x + v.y + v.z + v.w;
    }
    float mean = s * 0.01f;
    float vs = 0.f, mx = -1e30f;
#pragma unroll
    for (int t4 = 0; t4 < 25; ++t4) {
      float4 v = *(const float4*)(row + t4 * 4);
      float d0 = v.x-mean, d1 = v.y-mean, d2 = v.z-mean, d3 = v.w-mean;
      vs += d0*d0 + d1*d1 + d2*d2 + d3*d3;
      mx = fmaxf(mx, fmaxf(fmaxf(d0, d1), fmaxf(d2, d3)));
    }
    float inv = 1.f / (5.f * sqrtf(vs * (1.f / 99.f) + 1e-5f));
    float es = 0.f;
#pragma unroll
    for (int t4 = 0; t4 < 25; ++t4) {
      float4 v = *(const float4*)(row + t4 * 4);
      float4 e;
      e.x = expf((v.x - mean - mx) * inv);
      e.y = expf((v.y - mean - mx) * inv);
      e.z = expf((v.z - mean - mx) * inv);
      e.w = expf((v.w - mean - mx) * inv);
      es += e.x + e.y + e.z + e.w;
      *(float4*)(row + t4 * 4) = e;
    }
    rcps[tid] = 1.f / es;
  }
  __syncthreads();
  // attn[ij] = sum_hw p[hw][ij]
  if (tid < 100) {
    float s = 0.f;
    for (int hw = 0; hw < 100; ++hw) s += c1[hw * 100 + tid] * rcps[hw];
    attn[q * 100 + tid] = s;
  }
}

// ------- att_mem[b,n,c] = sum_ij attn*feat_m/100 (blk<400); enc (blk>=400) ----
__global__ void k_attmem_enc(const float* __restrict__ attn, const float* __restrict__ fmg,
                             const float* __restrict__ fbg,
                             float* __restrict__ am, float* __restrict__ enc) {
  int blk = blockIdx.x;
  if (blk < 400) {
    int n = blk % 50;
    __shared__ float a[100];
    if (threadIdx.x < 100) a[threadIdx.x] = attn[blk * 100 + threadIdx.x];
    __syncthreads();
    for (int c = threadIdx.x; c < 640; c += 256) {
      const float4* fp = (const float4*)(fmg + (n * 640 + c) * 100);
      float s = 0.f;
#pragma unroll
      for (int t4 = 0; t4 < 25; ++t4) {
        float4 v = fp[t4];
        s += a[t4*4]*v.x + a[t4*4+1]*v.y + a[t4*4+2]*v.z + a[t4*4+3]*v.w;
      }
      am[blk * 640 + c] = s * 0.01f;
    }
  } else {
    int bb = blk - 400;
    for (int c = threadIdx.x; c < 640; c += 256) {
      const float4* fp = (const float4*)(fbg + (bb * 640 + c) * 100);
      float s = 0.f;
#pragma unroll
      for (int t4 = 0; t4 < 25; ++t4) {
        float4 v = fp[t4];
        s += v.x + v.y + v.z + v.w;
      }
      enc[bb * 640 + c] = s * 0.01f;
    }
  }
}

// ------- final: cosine-sim softmax over memory + mem_vec + FC logits ---------
__global__ void k_final(const float* __restrict__ enc, const float* __restrict__ am,
                        const float* __restrict__ Wfc, const float* __restrict__ bfc,
                        float* __restrict__ out) {
  int b = blockIdx.x, tid = threadIdx.x;
  __shared__ float cat[1280];      // [0,640) = enc, [640,1280) = mem_vec
  __shared__ float wsm[50];
  __shared__ float wred[4];
  for (int c = tid; c < 640; c += 256) cat[c] = enc[b * 640 + c];
  __syncthreads();
  float ps = 0.f;
  for (int c = tid; c < 640; c += 256) { float x = cat[c]; ps += x * x; }
  for (int off = 32; off; off >>= 1) ps += __shfl_down(ps, off);
  if ((tid & 63) == 0) wred[tid >> 6] = ps;
  __syncthreads();
  float en = fmaxf(sqrtf(wred[0] + wred[1] + wred[2] + wred[3]), 1e-8f);
  if (tid < 50) {
    const float* ap = am + (b * 50 + tid) * 640;
    float dot = 0.f, nn = 0.f;
    for (int c = 0; c < 640; ++c) { float x = ap[c]; dot += x * cat[c]; nn += x * x; }
    wsm[tid] = dot / (en * fmaxf(sqrtf(nn), 1e-8f));
  }
  __syncthreads();
  if (tid == 0) {
    float mx = -1e30f;
    for (int n2 = 0; n2 < 50; ++n2) mx = fmaxf(mx, wsm[n2]);
    float es = 0.f;
    for (int n2 = 0; n2 < 50; ++n2) { float ex = expf(wsm[n2] - mx); wsm[n2] = ex; es += ex; }
    float rr = 1.f / es;
    for (int n2 = 0; n2 < 50; ++n2) wsm[n2] *= rr;
  }
  __syncthreads();
  for (int c = tid; c < 640; c += 256) {
    float s = 0.f;
    for (int n2 = 0; n2 < 50; ++n2) s += wsm[n2] * am[(b * 50 + n2) * 640 + c];
    cat[640 + c] = s;
  }
  __syncthreads();
  // logits: thread t<250 owns j = 4t..4t+3 (float4 W loads, coalesced)
  if (tid < 250) {
    int j0 = tid * 4;
    float4 s = *(const float4*)(bfc + j0);
    for (int c = 0; c < 1280; ++c) {
      float cc = cat[c];
      float4 w4 = *(const float4*)(Wfc + c * 1000 + j0);
      s.x += cc * w4.x; s.y += cc * w4.y; s.z += cc * w4.z; s.w += cc * w4.w;
    }
    *(float4*)(out + b * 1000 + j0) = s;
  }
}

extern "C" void kernel_launch(void* const* d_in, const int* in_sizes, int n_in,
                              void* d_out, int out_size, void* d_ws, size_t ws_size,
                              hipStream_t stream) {
  const float* feat_b = (const float*)d_in[0];
  const float* feat_m = (const float*)d_in[1];
  const float* w1x1   = (const float*)d_in[2];
  const float* bns    = (const float*)d_in[3];
  const float* bnb    = (const float*)d_in[4];
  const float* w1h    = (const float*)d_in[5];
  const float* w1u    = (const float*)d_in[6];
  const float* w2h    = (const float*)d_in[7];
  const float* w2u    = (const float*)d_in[8];
  const float* Wfc    = (const float*)d_in[9];
  const float* bfc    = (const float*)d_in[10];
  float* ws = (float*)d_ws;
  float* fbW  = ws + WS_FB;   float* fmW  = ws + WS_FM;
  float* attn = ws + WS_ATTN; float* am   = ws + WS_AM;
  float* enc  = ws + WS_ENC;

  k_embed      <<<580,  64, 0, stream>>>(feat_b, feat_m, w1x1, bns, bnb, fbW, fmW);
  k_mid        <<<400, 256, 0, stream>>>(fbW, fmW, w1h, w1u, w2h, w2u, attn);
  k_attmem_enc <<<408, 256, 0, stream>>>(attn, feat_m, feat_b, am, enc);
  k_final      <<<8,   256, 0, stream>>>(enc, am, Wfc, bfc, (float*)d_out);
}

// Round 5
// 352.532 us; speedup vs baseline: 5.2082x; 1.7119x over previous
//
#include <hip/hip_runtime.h>

// ---------------- workspace layout (floats) ----------------
#define WS_FB    0          // 8*100*64   fb [b][hw][o]
#define WS_FM    51200      // 50*100*64  fm [n][ij][o]
#define WS_ATTN  371200     // 400*100 attn_memory [q][ij]
#define WS_AM    411200     // 8*50*640 att_mem [b][n][c]
#define WS_ENC   667200     // 8*640

// ---------------- embed: mean-shift + 1x1 conv + BN + ReLU + L2 norm ----------
__global__ void k_embed(const float* __restrict__ fbg, const float* __restrict__ fmg,
                        const float* __restrict__ w1x1,
                        const float* __restrict__ bns, const float* __restrict__ bnb,
                        float* __restrict__ fb, float* __restrict__ fm) {
  int lane = threadIdx.x;
  int pos0 = blockIdx.x * 10;
  const float* src; float* dst; int hw0;
  if (pos0 < 800) { int img = pos0 / 100; hw0 = pos0 % 100; src = fbg + img * 64000; dst = fb + pos0 * 64; }
  else { int p = pos0 - 800; int img = p / 100; hw0 = p % 100; src = fmg + img * 64000; dst = fm + p * 64; }

  __shared__ float xs[10][640];
  float lsum[10];
#pragma unroll
  for (int p = 0; p < 10; ++p) lsum[p] = 0.f;
  for (int i = 0; i < 10; ++i) {
    int c = lane + i * 64;
    const float* sp = src + c * 100 + hw0;
#pragma unroll
    for (int p = 0; p < 10; p += 2) {
      float2 v = *(const float2*)(sp + p);
      xs[p][c] = v.x; xs[p + 1][c] = v.y;
      lsum[p] += v.x; lsum[p + 1] += v.y;
    }
  }
  float mean[10];
#pragma unroll
  for (int p = 0; p < 10; ++p) {
    float s = lsum[p];
    for (int off = 32; off; off >>= 1) s += __shfl_down(s, off);
    mean[p] = __shfl(s, 0) * (1.f / 640.f);
  }
  __syncthreads();
  float acc[10];
#pragma unroll
  for (int p = 0; p < 10; ++p) acc[p] = 0.f;
  float wsl = 0.f;
  const float* wrow = w1x1 + lane * 640;
  for (int c4 = 0; c4 < 160; ++c4) {
    float4 w4 = *(const float4*)(wrow + c4 * 4);
    wsl += w4.x + w4.y + w4.z + w4.w;
#pragma unroll
    for (int p = 0; p < 10; ++p) {
      float4 x4 = *(const float4*)(&xs[p][c4 * 4]);
      acc[p] += w4.x * x4.x + w4.y * x4.y + w4.z * x4.z + w4.w * x4.w;
    }
  }
  float sc = bns[lane], bi = bnb[lane];
#pragma unroll
  for (int p = 0; p < 10; ++p) {
    float y = (acc[p] - mean[p] * wsl) * sc + bi;
    y = fmaxf(y, 0.f);
    float sq = y * y;
    for (int off = 32; off; off >>= 1) sq += __shfl_down(sq, off);
    float nrm = sqrtf(__shfl(sq, 0));
    dst[p * 64 + lane] = y / fmaxf(nrm, 1e-8f);
  }
}

// ================= fused corr + sep-conv4d(x2) + attn-softmax ================
// 256 threads, 1 block/CU. Thread t<250 owns a 2x2 uv patch at fixed h.
// Register cache: 12 PERIMETER uv-rows (120 VGPR, k-invariant) + acc (40).
// Own-center rows + h+-1 rows re-read per k from LDS (b128). Peak live ~230
// VGPR < 256 architectural cap -> no scratch spill (the R4 killer).

#define LOAD_ROW12(DST, BASE, OFFW, OK) {                                   \
    int _o = (OK) ? (OFFW) : 0;                                             \
    float4 _a = *(const float4*)((BASE) + _o);                              \
    float4 _b = *(const float4*)((BASE) + _o + 4);                          \
    float4 _c = *(const float4*)((BASE) + _o + 8);                          \
    if (!(OK)) { _a = make_float4(0,0,0,0); _b = _a; _c = _a; }             \
    DST[0]=_a.x; DST[1]=_a.y; DST[2]=_a.z; DST[3]=_a.w;                     \
    DST[4]=_b.x; DST[5]=_b.y; DST[6]=_b.z; DST[7]=_b.w;                     \
    DST[8]=_c.x; DST[9]=_c.y; }

#define HW_TAPS(OUT, ROW, W0, W1, W2) {                                     \
    _Pragma("unroll") for (int w = 1; w < 10; ++w) OUT[w] += (W0)*ROW[w-1]; \
    _Pragma("unroll") for (int w = 0; w < 10; ++w) OUT[w] += (W1)*ROW[w];   \
    _Pragma("unroll") for (int w = 0; w < 9;  ++w) OUT[w] += (W2)*ROW[w+1]; }

// distribute row at grid pos (uu,vv) into the 4 own accumulators
#define UV_TAPS(ACCARR, ROW, WARR) {                                        \
    _Pragma("unroll") for (int i = 0; i < 2; ++i) {                         \
      _Pragma("unroll") for (int j = 0; j < 2; ++j) {                       \
        int du = uu - 1 - i, dv = vv - 1 - j;                               \
        if (du >= -1 && du <= 1 && dv >= -1 && dv <= 1) {                   \
          float wgt = WARR[(du+1)*3 + (dv+1)];                              \
          _Pragma("unroll") for (int w = 0; w < 10; ++w)                    \
            ACCARR[i*2+j][w] += wgt * ROW[w];                               \
        } } } }

__global__ __launch_bounds__(256, 1) void k_mid(
    const float* __restrict__ fb, const float* __restrict__ fm,
    const float* __restrict__ w1h_g, const float* __restrict__ w1u_g,
    const float* __restrict__ w2h_g, const float* __restrict__ w2u_g,
    float* __restrict__ attn)
{
  __shared__ float xs[12000];    // corr rows (ij*10+h), stride 12
  __shared__ float c1[12000];    // per-k hidden; later T[100][108]
  __shared__ float fbS[6800];    // fb rows, stride 68
  __shared__ float rcps[100];
  const int tid = threadIdx.x, q = blockIdx.x;
  const int b = q / 50, n = q % 50;

  const bool act = tid < 250;
  const int pu = tid / 50, prem = tid % 50, pv = prem / 10, h = prem % 10;
  const int u0 = pu * 2, v0 = pv * 2;
  const int ij0 = u0 * 10 + v0;

  // ---- stage fb rows ----
  for (int i = tid; i < 1600; i += 256) {
    int hw = i >> 4, c4 = (i & 15) << 2;
    *(float4*)(fbS + hw * 68 + c4) = *(const float4*)(fb + b * 6400 + hw * 64 + c4);
  }
  __syncthreads();

  // ---- corr: 2 passes, each computes 2 ij rows (fm pair in regs) ----
#pragma unroll 1
  for (int pass = 0; pass < 2; ++pass) {
    if (act) {
      int ijb = ij0 + pass * 10;
      float fmA[64], fmB[64];
      const float* p0 = fm + n * 6400 + ijb * 64;
#pragma unroll
      for (int c4 = 0; c4 < 16; ++c4) {
        float4 vA = *(const float4*)(p0 + c4 * 4);
        float4 vB = *(const float4*)(p0 + 64 + c4 * 4);
        fmA[c4*4+0]=vA.x; fmA[c4*4+1]=vA.y; fmA[c4*4+2]=vA.z; fmA[c4*4+3]=vA.w;
        fmB[c4*4+0]=vB.x; fmB[c4*4+1]=vB.y; fmB[c4*4+2]=vB.z; fmB[c4*4+3]=vB.w;
      }
      float a0[10], a1[10];
#pragma unroll
      for (int w = 0; w < 10; ++w) {
        const float* rw = fbS + (h * 10 + w) * 68;
        float s0 = 0.f, s1 = 0.f;
#pragma unroll
        for (int c4 = 0; c4 < 16; ++c4) {
          float4 v = *(const float4*)(rw + c4 * 4);
          s0 += v.x*fmA[4*c4] + v.y*fmA[4*c4+1] + v.z*fmA[4*c4+2] + v.w*fmA[4*c4+3];
          s1 += v.x*fmB[4*c4] + v.y*fmB[4*c4+1] + v.z*fmB[4*c4+2] + v.w*fmB[4*c4+3];
        }
        a0[w] = s0; a1[w] = s1;
      }
      float* r0p = xs + (ijb * 10 + h) * 12;
      *(float4*)(r0p)     = make_float4(a0[0],a0[1],a0[2],a0[3]);
      *(float4*)(r0p + 4) = make_float4(a0[4],a0[5],a0[6],a0[7]);
      *(float4*)(r0p + 8) = make_float4(a0[8],a0[9],0.f,0.f);
      float* r1p = xs + ((ijb + 1) * 10 + h) * 12;
      *(float4*)(r1p)     = make_float4(a1[0],a1[1],a1[2],a1[3]);
      *(float4*)(r1p + 4) = make_float4(a1[4],a1[5],a1[6],a1[7]);
      *(float4*)(r1p + 8) = make_float4(a1[8],a1[9],0.f,0.f);
    }
  }
  __syncthreads();             // xs (corr) ready

  // ---- register cache: 12 PERIMETER rows of the 4x4 uv neighborhood ----
  // X[uu][vv] valid only when uu in {0,3} or vv in {0,3}; center 4 untouched
  // (constant indices everywhere -> SROA drops the unused 40 regs).
  float X[4][4][10];
  float acc[4][10];
  if (act) {
#pragma unroll
    for (int uu = 0; uu < 4; ++uu)
#pragma unroll
      for (int vv = 0; vv < 4; ++vv) {
        if (uu >= 1 && uu <= 2 && vv >= 1 && vv <= 2) continue;  // center: not cached
        int up = u0 - 1 + uu, vp = v0 - 1 + vv;
        bool ok = (up >= 0) && (up < 10) && (vp >= 0) && (vp < 10);
        LOAD_ROW12(X[uu][vv], xs, ((up * 10 + vp) * 10 + h) * 12, ok);
      }
#pragma unroll
    for (int oi = 0; oi < 4; ++oi)
#pragma unroll
      for (int w = 0; w < 10; ++w) acc[oi][w] = 0.f;
  }

  for (int k = 0; k < 16; ++k) {
    float wA[9], wB[9];
#pragma unroll
    for (int t = 0; t < 9; ++t) { wA[t] = w1h_g[k * 9 + t]; wB[t] = w1u_g[k * 9 + t]; }
    if (act) {
      // own-center rows for this k (transient)
      float O4[4][10];
#pragma unroll
      for (int i = 0; i < 2; ++i)
#pragma unroll
        for (int j = 0; j < 2; ++j)
          LOAD_ROW12(O4[i*2+j], xs, (((u0+i)*10 + (v0+j))*10 + h) * 12, true);
      // conv1 per owned row
#pragma unroll
      for (int i = 0; i < 2; ++i)
#pragma unroll
        for (int j = 0; j < 2; ++j) {
          int oi = i*2+j;
          float o[10];
#pragma unroll
          for (int w = 0; w < 10; ++w) o[w] = 0.f;
          // hw taps: center from O4, h+-1 from LDS
          HW_TAPS(o, O4[oi], wA[3], wA[4], wA[5]);
          {
            float R[10];
            int hm = h - 1; bool okm = hm >= 0;
            LOAD_ROW12(R, xs, (((u0+i)*10 + (v0+j))*10 + hm) * 12, okm);
            HW_TAPS(o, R, wA[0], wA[1], wA[2]);
            int hp = h + 1; bool okp = hp < 10;
            LOAD_ROW12(R, xs, (((u0+i)*10 + (v0+j))*10 + hp) * 12, okp);
            HW_TAPS(o, R, wA[6], wA[7], wA[8]);
          }
          // uv taps: center region from O4, perimeter from X cache
#pragma unroll
          for (int du = -1; du <= 1; ++du)
#pragma unroll
            for (int dv = -1; dv <= 1; ++dv) {
              int ii = i + du, jj = j + dv;       // own-grid coords
              float wgt = wB[(du+1)*3 + (dv+1)];
              if (ii >= 0 && ii <= 1 && jj >= 0 && jj <= 1) {
#pragma unroll
                for (int w = 0; w < 10; ++w) o[w] += wgt * O4[ii*2+jj][w];
              } else {
#pragma unroll
                for (int w = 0; w < 10; ++w) o[w] += wgt * X[1+ii][1+jj][w];
              }
            }
          // relu -> c1
          float* cp = c1 + (((u0+i)*10 + (v0+j))*10 + h) * 12;
          float4 w0 = make_float4(fmaxf(o[0],0.f), fmaxf(o[1],0.f), fmaxf(o[2],0.f), fmaxf(o[3],0.f));
          float4 w1 = make_float4(fmaxf(o[4],0.f), fmaxf(o[5],0.f), fmaxf(o[6],0.f), fmaxf(o[7],0.f));
          float4 w2 = make_float4(fmaxf(o[8],0.f), fmaxf(o[9],0.f), 0.f, 0.f);
          *(float4*)(cp) = w0; *(float4*)(cp + 4) = w1; *(float4*)(cp + 8) = w2;
        }
    }
    __syncthreads();
    // conv2 weights
#pragma unroll
    for (int t = 0; t < 9; ++t) { wA[t] = w2h_g[k * 9 + t]; wB[t] = w2u_g[k * 9 + t]; }
    if (act) {
      // unified 4x4 grid pass: uv taps for all; own rows also get hw-center
#pragma unroll
      for (int uu = 0; uu < 4; ++uu)
#pragma unroll
        for (int vv = 0; vv < 4; ++vv) {
          float R[10];
          int up = u0 - 1 + uu, vp = v0 - 1 + vv;
          bool ok = (up >= 0) && (up < 10) && (vp >= 0) && (vp < 10);
          LOAD_ROW12(R, c1, ((up*10 + vp)*10 + h) * 12, ok);
          UV_TAPS(acc, R, wB);
          if (uu >= 1 && uu <= 2 && vv >= 1 && vv <= 2) {
            int oi = (uu-1)*2 + (vv-1);
            HW_TAPS(acc[oi], R, wA[3], wA[4], wA[5]);
          }
        }
      // hw h+-1 taps per owned row
#pragma unroll
      for (int i = 0; i < 2; ++i)
#pragma unroll
        for (int j = 0; j < 2; ++j) {
          int oi = i*2+j;
          float R[10];
          int hm = h - 1; bool okm = hm >= 0;
          LOAD_ROW12(R, c1, (((u0+i)*10 + (v0+j))*10 + hm) * 12, okm);
          HW_TAPS(acc[oi], R, wA[0], wA[1], wA[2]);
          int hp = h + 1; bool okp = hp < 10;
          LOAD_ROW12(R, c1, (((u0+i)*10 + (v0+j))*10 + hp) * 12, okp);
          HW_TAPS(acc[oi], R, wA[6], wA[7], wA[8]);
        }
    }
    __syncthreads();
  }

  // ---- attn: write conv output transposed T[hw][ij] (stride 108) ----
  if (act) {
#pragma unroll
    for (int i = 0; i < 2; ++i)
#pragma unroll
      for (int j = 0; j < 2; ++j) {
        int ij = (u0 + i) * 10 + (v0 + j);
#pragma unroll
        for (int w = 0; w < 10; ++w) c1[(h*10 + w)*108 + ij] = acc[i*2+j][w];
      }
  }
  __syncthreads();
  // per-hw row: gaussian-normalize over ij (ddof=1), /5, softmax
  if (tid < 100) {
    float* row = c1 + tid * 108;
    float s = 0.f;
#pragma unroll
    for (int t4 = 0; t4 < 25; ++t4) {
      float4 v = *(const float4*)(row + t4 * 4);
      s += v.x + v.y + v.z + v.w;
    }
    float mean = s * 0.01f;
    float vs = 0.f, mx = -1e30f;
#pragma unroll
    for (int t4 = 0; t4 < 25; ++t4) {
      float4 v = *(const float4*)(row + t4 * 4);
      float d0 = v.x-mean, d1 = v.y-mean, d2 = v.z-mean, d3 = v.w-mean;
      vs += d0*d0 + d1*d1 + d2*d2 + d3*d3;
      mx = fmaxf(mx, fmaxf(fmaxf(d0, d1), fmaxf(d2, d3)));
    }
    float inv = 1.f / (5.f * sqrtf(vs * (1.f / 99.f) + 1e-5f));
    float es = 0.f;
#pragma unroll
    for (int t4 = 0; t4 < 25; ++t4) {
      float4 v = *(const float4*)(row + t4 * 4);
      float4 e;
      e.x = expf((v.x - mean - mx) * inv);
      e.y = expf((v.y - mean - mx) * inv);
      e.z = expf((v.z - mean - mx) * inv);
      e.w = expf((v.w - mean - mx) * inv);
      es += e.x + e.y + e.z + e.w;
      *(float4*)(row + t4 * 4) = e;
    }
    rcps[tid] = 1.f / es;
  }
  __syncthreads();
  if (tid < 100) {
    float s = 0.f;
    for (int hw = 0; hw < 100; ++hw) s += c1[hw * 108 + tid] * rcps[hw];
    attn[q * 100 + tid] = s;
  }
}

// ------- att_mem[b,n,c] = sum_ij attn*feat_m/100 (blk<400); enc (blk>=400) ----
__global__ void k_attmem_enc(const float* __restrict__ attn, const float* __restrict__ fmg,
                             const float* __restrict__ fbg,
                             float* __restrict__ am, float* __restrict__ enc) {
  int blk = blockIdx.x;
  if (blk < 400) {
    int n = blk % 50;
    __shared__ float a[100];
    if (threadIdx.x < 100) a[threadIdx.x] = attn[blk * 100 + threadIdx.x];
    __syncthreads();
    for (int c = threadIdx.x; c < 640; c += 256) {
      const float4* fp = (const float4*)(fmg + (n * 640 + c) * 100);
      float s = 0.f;
#pragma unroll
      for (int t4 = 0; t4 < 25; ++t4) {
        float4 v = fp[t4];
        s += a[t4*4]*v.x + a[t4*4+1]*v.y + a[t4*4+2]*v.z + a[t4*4+3]*v.w;
      }
      am[blk * 640 + c] = s * 0.01f;
    }
  } else {
    int bb = blk - 400;
    for (int c = threadIdx.x; c < 640; c += 256) {
      const float4* fp = (const float4*)(fbg + (bb * 640 + c) * 100);
      float s = 0.f;
#pragma unroll
      for (int t4 = 0; t4 < 25; ++t4) {
        float4 v = fp[t4];
        s += v.x + v.y + v.z + v.w;
      }
      enc[bb * 640 + c] = s * 0.01f;
    }
  }
}

// ------- final: cosine-sim softmax over memory + mem_vec + FC logits ---------
__global__ void k_final(const float* __restrict__ enc, const float* __restrict__ am,
                        const float* __restrict__ Wfc, const float* __restrict__ bfc,
                        float* __restrict__ out) {
  int b = blockIdx.x, tid = threadIdx.x;
  __shared__ float cat[1280];
  __shared__ float wsm[50];
  __shared__ float wred[4];
  for (int c = tid; c < 640; c += 256) cat[c] = enc[b * 640 + c];
  __syncthreads();
  float ps = 0.f;
  for (int c = tid; c < 640; c += 256) { float x = cat[c]; ps += x * x; }
  for (int off = 32; off; off >>= 1) ps += __shfl_down(ps, off);
  if ((tid & 63) == 0) wred[tid >> 6] = ps;
  __syncthreads();
  float en = fmaxf(sqrtf(wred[0] + wred[1] + wred[2] + wred[3]), 1e-8f);
  if (tid < 50) {
    const float* ap = am + (b * 50 + tid) * 640;
    float dot = 0.f, nn = 0.f;
    for (int c = 0; c < 640; ++c) { float x = ap[c]; dot += x * cat[c]; nn += x * x; }
    wsm[tid] = dot / (en * fmaxf(sqrtf(nn), 1e-8f));
  }
  __syncthreads();
  if (tid == 0) {
    float mx = -1e30f;
    for (int n2 = 0; n2 < 50; ++n2) mx = fmaxf(mx, wsm[n2]);
    float es = 0.f;
    for (int n2 = 0; n2 < 50; ++n2) { float ex = expf(wsm[n2] - mx); wsm[n2] = ex; es += ex; }
    float rr = 1.f / es;
    for (int n2 = 0; n2 < 50; ++n2) wsm[n2] *= rr;
  }
  __syncthreads();
  for (int c = tid; c < 640; c += 256) {
    float s = 0.f;
    for (int n2 = 0; n2 < 50; ++n2) s += wsm[n2] * am[(b * 50 + n2) * 640 + c];
    cat[640 + c] = s;
  }
  __syncthreads();
  if (tid < 250) {
    int j0 = tid * 4;
    float4 s = *(const float4*)(bfc + j0);
    for (int c = 0; c < 1280; ++c) {
      float cc = cat[c];
      float4 w4 = *(const float4*)(Wfc + c * 1000 + j0);
      s.x += cc * w4.x; s.y += cc * w4.y; s.z += cc * w4.z; s.w += cc * w4.w;
    }
    *(float4*)(out + b * 1000 + j0) = s;
  }
}

extern "C" void kernel_launch(void* const* d_in, const int* in_sizes, int n_in,
                              void* d_out, int out_size, void* d_ws, size_t ws_size,
                              hipStream_t stream) {
  const float* feat_b = (const float*)d_in[0];
  const float* feat_m = (const float*)d_in[1];
  const float* w1x1   = (const float*)d_in[2];
  const float* bns    = (const float*)d_in[3];
  const float* bnb    = (const float*)d_in[4];
  const float* w1h    = (const float*)d_in[5];
  const float* w1u    = (const float*)d_in[6];
  const float* w2h    = (const float*)d_in[7];
  const float* w2u    = (const float*)d_in[8];
  const float* Wfc    = (const float*)d_in[9];
  const float* bfc    = (const float*)d_in[10];
  float* ws = (float*)d_ws;
  float* fbW  = ws + WS_FB;   float* fmW  = ws + WS_FM;
  float* attn = ws + WS_ATTN; float* am   = ws + WS_AM;
  float* enc  = ws + WS_ENC;

  k_embed      <<<580,  64, 0, stream>>>(feat_b, feat_m, w1x1, bns, bnb, fbW, fmW);
  k_mid        <<<400, 256, 0, stream>>>(fbW, fmW, w1h, w1u, w2h, w2u, attn);
  k_attmem_enc <<<408, 256, 0, stream>>>(attn, feat_m, feat_b, am, enc);
  k_final      <<<8,   256, 0, stream>>>(enc, am, Wfc, bfc, (float*)d_out);
}